// Round 1
// baseline (159.905 us; speedup 1.0000x reference)
//
#include <hip/hip_runtime.h>
#include <stdint.h>

#define BS 8192
#define DD 128
#define SPLIT 8

typedef __attribute__((ext_vector_type(8))) short short8;
typedef __attribute__((ext_vector_type(4))) float float4v;

__device__ __forceinline__ float bf2f(short s) {
  union { unsigned u; float f; } c;
  c.u = ((unsigned)(unsigned short)s) << 16;
  return c.f;
}
__device__ __forceinline__ short f2bf(float f) {
  union { float f; unsigned u; } c; c.f = f;
  unsigned u = c.u + 0x7FFFu + ((c.u >> 16) & 1u);
  return (short)(u >> 16);
}

// K1: normalize rows (f32 + bf16 copies), accumulate per-class column sums h0/h1
// and class counts. 64 blocks x 256 thr; each wave handles 32 rows, lane owns
// columns {lane, lane+64} so class sums accumulate in registers (no per-row atomics).
__global__ __launch_bounds__(256) void k_norm(const float* __restrict__ data,
                                              const int* __restrict__ label,
                                              unsigned short* __restrict__ xnb,
                                              float* __restrict__ xnf,
                                              float* __restrict__ gh,
                                              int* __restrict__ cnt) {
  __shared__ float sh[256];
  __shared__ int shc[2];
  int tid = threadIdx.x, wave = tid >> 6, lane = tid & 63;
  if (tid < 2) shc[tid] = 0;
  sh[tid] = 0.f;
  __syncthreads();
  float a00 = 0.f, a01 = 0.f, a10 = 0.f, a11 = 0.f;
  int c0 = 0, c1 = 0;
  int rbase = blockIdx.x * 128 + wave * 32;
  for (int r = 0; r < 32; ++r) {
    int row = rbase + r;
    float v0 = data[row * DD + lane], v1 = data[row * DD + 64 + lane];
    float ss = v0 * v0 + v1 * v1;
    for (int off = 32; off; off >>= 1) ss += __shfl_xor(ss, off);
    float rn = 1.f / fmaxf(sqrtf(ss), 1e-12f);  // F.normalize eps clamp
    float x0 = v0 * rn, x1 = v1 * rn;
    xnf[row * DD + lane] = x0;
    xnf[row * DD + 64 + lane] = x1;
    xnb[row * DD + lane] = (unsigned short)f2bf(x0);
    xnb[row * DD + 64 + lane] = (unsigned short)f2bf(x1);
    int lab = label[row];  // wave-uniform
    if (lab == 0) { a00 += x0; a01 += x1; c0++; }
    else          { a10 += x0; a11 += x1; c1++; }
  }
  atomicAdd(&sh[lane], a00);        // h0[k=lane]
  atomicAdd(&sh[64 + lane], a01);   // h0[k=64+lane]
  atomicAdd(&sh[128 + lane], a10);  // h1[k=lane]
  atomicAdd(&sh[192 + lane], a11);  // h1[k=64+lane]
  if (lane == 0) { atomicAdd(&shc[0], c0); atomicAdd(&shc[1], c1); }
  __syncthreads();
  atomicAdd(&gh[tid], sh[tid]);
  if (tid < 2) atomicAdd(&cnt[tid], shc[tid]);
}

// K3: flash-style Gram-row reductions. Block = (row-block rb of 64 rows) x (j-slice sl
// of 1024 cols). 4 waves x 16 rows. A-frags (pre-scaled by exp(scale)) live in regs;
// B tiles (64x128 bf16 = 16 KB, contiguous in global) staged via global_load_lds.
__global__ __launch_bounds__(256) void k_main(const unsigned short* __restrict__ xnb,
                                              const int* __restrict__ label,
                                              const float* __restrict__ scale,
                                              float* __restrict__ Zr,
                                              float* __restrict__ Ur,
                                              float* __restrict__ Vr) {
  __shared__ short tile[64 * DD];  // 16 KB, same linear layout as global
  int tid = threadIdx.x, wave = tid >> 6, lane = tid & 63;
  int quad = lane >> 4, col = lane & 15;
  int rb = blockIdx.x / SPLIT, sl = blockIdx.x % SPLIT;
  float se = __expf(scale[0]);

  // A fragment: A[m=lane&15][k=quad*8+i], ktiles t=0..3 cover K=128
  int arow = rb * 64 + wave * 16 + col;
  const short* ap = (const short*)xnb + (size_t)arow * DD;
  short8 afrag[4];
#pragma unroll
  for (int t = 0; t < 4; ++t) {
    short8 a = *(const short8*)(ap + t * 32 + quad * 8);
#pragma unroll
    for (int i = 0; i < 8; ++i) a[i] = f2bf(bf2f(a[i]) * se);  // fold exp(scale) into A
    afrag[t] = a;
  }
  int labI[4];
#pragma unroll
  for (int r = 0; r < 4; ++r) labI[r] = label[rb * 64 + wave * 16 + quad * 4 + r];

  float Z[4] = {0, 0, 0, 0}, U[4] = {0, 0, 0, 0}, V0[4] = {0, 0, 0, 0};

  const char* srcbase = (const char*)xnb;
  for (int j0 = sl * (BS / SPLIT); j0 < (sl + 1) * (BS / SPLIT); j0 += 64) {
    __syncthreads();  // previous tile fully consumed
    const char* src = srcbase + (size_t)j0 * 256 + tid * 16;
    char* dst = ((char*)tile) + tid * 16;
#pragma unroll
    for (int p = 0; p < 4; ++p)
      __builtin_amdgcn_global_load_lds(
          (const __attribute__((address_space(1))) void*)(uintptr_t)(src + p * 4096),
          (__attribute__((address_space(3))) void*)(uintptr_t)(dst + p * 4096), 16, 0, 0);
    __syncthreads();  // drains vmcnt(0) before barrier -> tile visible
#pragma unroll
    for (int jo = 0; jo < 4; ++jo) {
      int jc = j0 + jo * 16 + col;
      float m0 = (label[jc] == 0) ? 1.f : 0.f;  // per-column mask, uniform over r
      float4v c = {0.f, 0.f, 0.f, 0.f};
      const short* bp = tile + (jo * 16 + col) * DD;
#pragma unroll
      for (int t = 0; t < 4; ++t) {
        short8 b = *(const short8*)(bp + t * 32 + quad * 8);
        c = __builtin_amdgcn_mfma_f32_16x16x32_bf16(afrag[t], b, c, 0, 0, 0);
      }
#pragma unroll
      for (int r = 0; r < 4; ++r) {  // C/D: col=lane&15, row=quad*4+r (m89-verified)
        float l = c[r];              // l = exp(scale) * cos_sim  (scale folded in A)
        float e = __expf(l);         // l <= 14.29 -> e <= 1.6e6, fp32-safe, no max needed
        Z[r] += e;
        U[r] += e * l;
        V0[r] += m0 * e;
      }
    }
  }
  // reduce across the 16 column-lanes sharing each row
#pragma unroll
  for (int r = 0; r < 4; ++r) {
#pragma unroll
    for (int off = 1; off < 16; off <<= 1) {
      Z[r] += __shfl_xor(Z[r], off);
      U[r] += __shfl_xor(U[r], off);
      V0[r] += __shfl_xor(V0[r], off);
    }
  }
  if (col == 0) {
#pragma unroll
    for (int r = 0; r < 4; ++r) {
      int row = rb * 64 + wave * 16 + quad * 4 + r;
      float v = (labI[r] == 0) ? V0[r] : (Z[r] - V0[r]);  // same-class sum-exp
      atomicAdd(&Zr[row], Z[r]);
      atomicAdd(&Ur[row], U[r]);
      atomicAdd(&Vr[row], v);
    }
  }
}

// K4: per-row loss. S,T via closed-form dots with class sums; M and log(Zq) cancel.
__global__ __launch_bounds__(256) void k_final(const float* __restrict__ xnf,
                                               const int* __restrict__ label,
                                               const float* __restrict__ scale,
                                               const float* __restrict__ gh,
                                               const int* __restrict__ cnt,
                                               const float* __restrict__ Zr,
                                               const float* __restrict__ Ur,
                                               const float* __restrict__ Vr,
                                               float* __restrict__ out) {
  __shared__ float bsum[4];
  int tid = threadIdx.x, wave = tid >> 6, lane = tid & 63;
  float se = __expf(scale[0]);
  float h0a = gh[lane], h0b = gh[64 + lane];
  float h1a = gh[128 + lane], h1b = gh[192 + lane];
  float ga = h0a + h1a, gb = h0b + h1b;  // g = h0 + h1
  float c0 = (float)cnt[0], c1 = (float)cnt[1];
  float local = 0.f;
  int rbase = blockIdx.x * 32 + wave * 8;
  for (int r = 0; r < 8; ++r) {
    int row = rbase + r;
    float x0 = xnf[row * DD + lane], x1 = xnf[row * DD + 64 + lane];
    int lab = label[row];
    float sg = x0 * ga + x1 * gb;
    float sh_ = (lab == 0) ? (x0 * h0a + x1 * h0b) : (x0 * h1a + x1 * h1b);
    for (int off = 32; off; off >>= 1) {
      sg += __shfl_xor(sg, off);
      sh_ += __shfl_xor(sh_, off);
    }
    if (lane == 0) {
      float cc = (lab == 0) ? c0 : c1;
      float a = __expf(1.f / cc);
      float Zq = cc * a + ((float)BS - cc);
      float S = se * sg, T = se * sh_;
      float Z = Zr[row], U = Ur[row], V = Vr[row];
      // loss_i = a/Zq - (S+(a-1)T)/Zq + U/Z - V/(c*Z)   (M_i, log Zq cancelled)
      local += a / Zq - (S + (a - 1.f) * T) / Zq + U / Z - V / (cc * Z);
    }
  }
  if (lane == 0) bsum[wave] = local;
  __syncthreads();
  if (tid == 0) {
    float s = bsum[0] + bsum[1] + bsum[2] + bsum[3];
    atomicAdd(out, s * (0.5f / (float)BS));
  }
}

extern "C" void kernel_launch(void* const* d_in, const int* in_sizes, int n_in,
                              void* d_out, int out_size, void* d_ws, size_t ws_size,
                              hipStream_t stream) {
  const float* data = (const float*)d_in[0];
  const float* scale = (const float*)d_in[1];
  const int* label = (const int*)d_in[2];
  char* ws = (char*)d_ws;
  // ws layout (bytes):
  //   0        xnb  bf16[8192*128]   2 MB
  //   2097152  xnf  f32 [8192*128]   4 MB
  //   6291456  Zr   f32 [8192]
  //   6324224  Ur   f32 [8192]
  //   6356992  Vr   f32 [8192]
  //   6389760  gh   f32 [256]  (h0[128], h1[128])
  //   6390784  cnt  int [2]
  unsigned short* xnb = (unsigned short*)ws;
  float* xnf = (float*)(ws + 2097152);
  float* Zr = (float*)(ws + 6291456);
  float* Ur = (float*)(ws + 6324224);
  float* Vr = (float*)(ws + 6356992);
  float* gh = (float*)(ws + 6389760);
  int* cnt = (int*)(ws + 6390784);

  hipMemsetAsync(ws + 6291456, 0, 99336, stream);  // accumulators
  hipMemsetAsync(d_out, 0, sizeof(float), stream);

  k_norm<<<64, 256, 0, stream>>>(data, label, xnb, xnf, gh, cnt);
  k_main<<<128 * SPLIT, 256, 0, stream>>>(xnb, label, scale, Zr, Ur, Vr);
  k_final<<<256, 256, 0, stream>>>(xnf, label, scale, gh, cnt, Zr, Ur, Vr, (float*)d_out);
}

// Round 2
// 122.104 us; speedup vs baseline: 1.3096x; 1.3096x over previous
//
#include <hip/hip_runtime.h>
#include <stdint.h>

#define BS 8192
#define DD 128
#define SPLIT 8

typedef __attribute__((ext_vector_type(8))) short short8;
typedef __attribute__((ext_vector_type(4))) float float4v;

__device__ __forceinline__ float bf2f(short s) {
  union { unsigned u; float f; } c;
  c.u = ((unsigned)(unsigned short)s) << 16;
  return c.f;
}
__device__ __forceinline__ short f2bf(float f) {
  union { float f; unsigned u; } c; c.f = f;
  unsigned u = c.u + 0x7FFFu + ((c.u >> 16) & 1u);
  return (short)(u >> 16);
}

// K1: normalize rows (f32 + packed-bf16 copies), per-class column sums, counts.
// 256 blocks x 4 waves x 8 rows. Lane owns columns {2*lane, 2*lane+1} (float2).
__global__ __launch_bounds__(256) void k_norm(const float* __restrict__ data,
                                              const int* __restrict__ label,
                                              unsigned int* __restrict__ xnb32,
                                              float* __restrict__ xnf,
                                              float* __restrict__ gh,
                                              int* __restrict__ cnt) {
  __shared__ float sh[256];
  __shared__ int shc[2];
  int tid = threadIdx.x, wave = tid >> 6, lane = tid & 63;
  if (tid < 2) shc[tid] = 0;
  sh[tid] = 0.f;
  __syncthreads();
  float a00 = 0.f, a01 = 0.f, a10 = 0.f, a11 = 0.f;
  int c0 = 0, c1 = 0;
  int rbase = blockIdx.x * 32 + wave * 8;
  for (int r = 0; r < 8; ++r) {
    int row = rbase + r;
    float2 v = *(const float2*)&data[row * DD + lane * 2];
    float ss = v.x * v.x + v.y * v.y;
    for (int off = 32; off; off >>= 1) ss += __shfl_xor(ss, off);
    float rn = 1.f / fmaxf(sqrtf(ss), 1e-12f);  // F.normalize eps clamp
    float x0 = v.x * rn, x1 = v.y * rn;
    *(float2*)&xnf[row * DD + lane * 2] = make_float2(x0, x1);
    unsigned int pk = (unsigned int)(unsigned short)f2bf(x0) |
                      ((unsigned int)(unsigned short)f2bf(x1) << 16);
    xnb32[row * 64 + lane] = pk;
    int lab = label[row];  // wave-uniform
    if (lab == 0) { a00 += x0; a01 += x1; c0++; }
    else          { a10 += x0; a11 += x1; c1++; }
  }
  atomicAdd(&sh[2 * lane], a00);            // h0[col=2*lane]
  atomicAdd(&sh[2 * lane + 1], a01);        // h0[col=2*lane+1]
  atomicAdd(&sh[128 + 2 * lane], a10);      // h1[...]
  atomicAdd(&sh[128 + 2 * lane + 1], a11);
  if (lane == 0) { atomicAdd(&shc[0], c0); atomicAdd(&shc[1], c1); }
  __syncthreads();
  atomicAdd(&gh[tid], sh[tid]);
  if (tid < 2) atomicAdd(&cnt[tid], shc[tid]);
}

// K3: flash-style Gram-row reductions with XOR-swizzled LDS tile.
// LDS position (row, c_pos) holds global 16B-chunk (row, c_pos ^ (row&15)).
// Staging: src_chunk = (tid&15) ^ (tid>>4), p-independent; dst stays linear
// (global_load_lds requires wave-uniform base + lane*16).
// Read: chunk for (t,quad) at col -> c_pos = (t*4+quad) ^ col  => every bank
// serves exactly 8 dwords per ds_read_b128 (wave64 conflict-free minimum).
__global__ __launch_bounds__(256) void k_main(const unsigned short* __restrict__ xnb,
                                              const int* __restrict__ label,
                                              const float* __restrict__ scale,
                                              float* __restrict__ Zr,
                                              float* __restrict__ Ur,
                                              float* __restrict__ Vr) {
  __shared__ short tile[64 * DD];  // 16 KB
  int tid = threadIdx.x, wave = tid >> 6, lane = tid & 63;
  int quad = lane >> 4, col = lane & 15;
  int rb = blockIdx.x / SPLIT, sl = blockIdx.x % SPLIT;
  float se = __expf(scale[0]);

  // A fragment: A[m=lane&15][k=quad*8+i], ktiles t=0..3 cover K=128
  int arow = rb * 64 + wave * 16 + col;
  const short* ap = (const short*)xnb + (size_t)arow * DD;
  short8 afrag[4];
#pragma unroll
  for (int t = 0; t < 4; ++t) {
    short8 a = *(const short8*)(ap + t * 32 + quad * 8);
#pragma unroll
    for (int i = 0; i < 8; ++i) a[i] = f2bf(bf2f(a[i]) * se);  // fold exp(scale) into A
    afrag[t] = a;
  }
  int labI[4];
#pragma unroll
  for (int r = 0; r < 4; ++r) labI[r] = label[rb * 64 + wave * 16 + quad * 4 + r];

  float Z[4] = {0, 0, 0, 0}, U[4] = {0, 0, 0, 0}, V0[4] = {0, 0, 0, 0};

  const char* srcbase = (const char*)xnb;
  int rowloc = tid >> 4;                  // 0..15: which row (mod 16) this lane stages
  int swz = (tid & 15) ^ rowloc;          // which 16B chunk of that row
  for (int j0 = sl * (BS / SPLIT); j0 < (sl + 1) * (BS / SPLIT); j0 += 64) {
    __syncthreads();  // previous tile fully consumed
    char* dst = ((char*)tile) + tid * 16;
#pragma unroll
    for (int p = 0; p < 4; ++p) {
      const char* src = srcbase + (size_t)(j0 + p * 16 + rowloc) * 256 + swz * 16;
      __builtin_amdgcn_global_load_lds(
          (const __attribute__((address_space(1))) void*)(uintptr_t)src,
          (__attribute__((address_space(3))) void*)(uintptr_t)(dst + p * 4096), 16, 0, 0);
    }
    __syncthreads();  // drains vmcnt(0) before barrier -> tile visible
#pragma unroll
    for (int jo = 0; jo < 4; ++jo) {
      int jc = j0 + jo * 16 + col;
      float m0 = (label[jc] == 0) ? 1.f : 0.f;  // per-column mask, uniform over r
      float4v c = {0.f, 0.f, 0.f, 0.f};
      const short* bp = tile + (jo * 16 + col) * DD;
#pragma unroll
      for (int t = 0; t < 4; ++t) {
        short8 b = *(const short8*)(bp + (((t * 4 + quad) ^ col)) * 8);
        c = __builtin_amdgcn_mfma_f32_16x16x32_bf16(afrag[t], b, c, 0, 0, 0);
      }
#pragma unroll
      for (int r = 0; r < 4; ++r) {  // C/D: col=lane&15, row=quad*4+r (m89-verified)
        float l = c[r];              // l = exp(scale) * cos_sim  (scale folded in A)
        float e = __expf(l);         // l <= 14.29 -> e <= 1.6e6, fp32-safe
        Z[r] += e;
        U[r] += e * l;
        V0[r] += m0 * e;
      }
    }
  }
  // reduce across the 16 column-lanes sharing each row
#pragma unroll
  for (int r = 0; r < 4; ++r) {
#pragma unroll
    for (int off = 1; off < 16; off <<= 1) {
      Z[r] += __shfl_xor(Z[r], off);
      U[r] += __shfl_xor(U[r], off);
      V0[r] += __shfl_xor(V0[r], off);
    }
  }
  if (col == 0) {
#pragma unroll
    for (int r = 0; r < 4; ++r) {
      int row = rb * 64 + wave * 16 + quad * 4 + r;
      float v = (labI[r] == 0) ? V0[r] : (Z[r] - V0[r]);  // same-class sum-exp
      atomicAdd(&Zr[row], Z[r]);
      atomicAdd(&Ur[row], U[r]);
      atomicAdd(&Vr[row], v);
    }
  }
}

// K4: per-row loss. S,T via closed-form dots with class sums; M and log(Zq) cancel.
// 256 blocks x 4 waves x 8 rows; lane owns columns {2*lane, 2*lane+1}.
__global__ __launch_bounds__(256) void k_final(const float* __restrict__ xnf,
                                               const int* __restrict__ label,
                                               const float* __restrict__ scale,
                                               const float* __restrict__ gh,
                                               const int* __restrict__ cnt,
                                               const float* __restrict__ Zr,
                                               const float* __restrict__ Ur,
                                               const float* __restrict__ Vr,
                                               float* __restrict__ out) {
  __shared__ float bsum[4];
  int tid = threadIdx.x, wave = tid >> 6, lane = tid & 63;
  float se = __expf(scale[0]);
  float h0a = gh[2 * lane], h0b = gh[2 * lane + 1];
  float h1a = gh[128 + 2 * lane], h1b = gh[128 + 2 * lane + 1];
  float ga = h0a + h1a, gb = h0b + h1b;  // g = h0 + h1
  float c0 = (float)cnt[0], c1 = (float)cnt[1];
  float local = 0.f;
  int rbase = blockIdx.x * 32 + wave * 8;
  for (int r = 0; r < 8; ++r) {
    int row = rbase + r;
    float2 x = *(const float2*)&xnf[row * DD + lane * 2];
    int lab = label[row];
    float sg = x.x * ga + x.y * gb;
    float sh_ = (lab == 0) ? (x.x * h0a + x.y * h0b) : (x.x * h1a + x.y * h1b);
    for (int off = 32; off; off >>= 1) {
      sg += __shfl_xor(sg, off);
      sh_ += __shfl_xor(sh_, off);
    }
    if (lane == 0) {
      float cc = (lab == 0) ? c0 : c1;
      float a = __expf(1.f / cc);
      float Zq = cc * a + ((float)BS - cc);
      float S = se * sg, T = se * sh_;
      float Z = Zr[row], U = Ur[row], V = Vr[row];
      // loss_i = a/Zq - (S+(a-1)T)/Zq + U/Z - V/(c*Z)   (M_i, log Zq cancelled)
      local += a / Zq - (S + (a - 1.f) * T) / Zq + U / Z - V / (cc * Z);
    }
  }
  if (lane == 0) bsum[wave] = local;
  __syncthreads();
  if (tid == 0) {
    float s = bsum[0] + bsum[1] + bsum[2] + bsum[3];
    atomicAdd(out, s * (0.5f / (float)BS));
  }
}

extern "C" void kernel_launch(void* const* d_in, const int* in_sizes, int n_in,
                              void* d_out, int out_size, void* d_ws, size_t ws_size,
                              hipStream_t stream) {
  const float* data = (const float*)d_in[0];
  const float* scale = (const float*)d_in[1];
  const int* label = (const int*)d_in[2];
  char* ws = (char*)d_ws;
  // ws layout (bytes):
  //   0        xnb  bf16[8192*128]   2 MB
  //   2097152  xnf  f32 [8192*128]   4 MB
  //   6291456  Zr   f32 [8192]
  //   6324224  Ur   f32 [8192]
  //   6356992  Vr   f32 [8192]
  //   6389760  gh   f32 [256]  (h0[128], h1[128])
  //   6390784  cnt  int [2]
  unsigned short* xnb = (unsigned short*)ws;
  unsigned int* xnb32 = (unsigned int*)ws;
  float* xnf = (float*)(ws + 2097152);
  float* Zr = (float*)(ws + 6291456);
  float* Ur = (float*)(ws + 6324224);
  float* Vr = (float*)(ws + 6356992);
  float* gh = (float*)(ws + 6389760);
  int* cnt = (int*)(ws + 6390784);

  hipMemsetAsync(ws + 6291456, 0, 99336, stream);  // accumulators
  hipMemsetAsync(d_out, 0, sizeof(float), stream);

  k_norm<<<256, 256, 0, stream>>>(data, label, xnb32, xnf, gh, cnt);
  k_main<<<128 * SPLIT, 256, 0, stream>>>(xnb, label, scale, Zr, Ur, Vr);
  k_final<<<256, 256, 0, stream>>>(xnf, label, scale, gh, cnt, Zr, Ur, Vr, (float*)d_out);
}